// Round 6
// baseline (164.675 us; speedup 1.0000x reference)
//
#include <hip/hip_runtime.h>

#define NN   16000
#define NE   64000
#define DIN  256
#define HD   64
#define DOUT 256
#define DE   128
#define KHD  32
#define BN_EPS 1e-5f

typedef __attribute__((ext_vector_type(8))) short bf16x8;
typedef __attribute__((ext_vector_type(4))) float f32x4;

__device__ __forceinline__ unsigned short f2bf(float f) {
    unsigned int u = __float_as_uint(f);
    u += 0x7fff + ((u >> 16) & 1);
    return (unsigned short)(u >> 16);
}
__device__ __forceinline__ float bf2f(unsigned short s) {
    return __uint_as_float(((unsigned int)s) << 16);
}

// ---------------- kernel P: pack all weights into bf16 MFMA layouts ----------------------
__global__ __launch_bounds__(256) void k_prep(
    const float* __restrict__ kw2, const float* __restrict__ kb2,
    const float* __restrict__ w1, const float* __restrict__ kw1, const float* __restrict__ w2,
    unsigned short* __restrict__ Wb, unsigned short* __restrict__ W0b,
    unsigned short* __restrict__ w1b, unsigned short* __restrict__ kw1b,
    unsigned short* __restrict__ w2b)
{
    int idx = blockIdx.x * 256 + threadIdx.x;
    if (idx < 33 * 4096) {
        int h = idx >> 12, r = idx & 4095;
        float v = (h < 32) ? kw2[(size_t)h * 4160 + 64 + r] : kb2[64 + r];
        Wb[idx] = f2bf(v);
        return;
    }
    idx -= 33 * 4096;
    if (idx < 2048) { int j = idx >> 5, h = idx & 31; W0b[idx] = f2bf(kw2[(size_t)h * 4160 + j]); return; }
    idx -= 2048;
    if (idx < 16384) { int j = idx >> 8, k = idx & 255; w1b[idx] = f2bf(w1[(size_t)k * 64 + j]); return; }
    idx -= 16384;
    if (idx < 4096) { int h = idx >> 7, k = idx & 127; kw1b[idx] = f2bf(kw1[(size_t)k * 32 + h]); return; }
    idx -= 4096;
    if (idx < 16384) { int c = idx >> 6, k = idx & 63; w2b[idx] = f2bf(w2[(size_t)k * 256 + c]); return; }
}

// ---------------- kernel A: msgn_b = bf16(relu(bn_msg(relu(bn_in(x)) @ w1 + b1))) --------
#define LNS 264
__global__ __launch_bounds__(256) void k_msgn(
    const float* __restrict__ x, const unsigned short* __restrict__ w1b,
    const float* __restrict__ b1,
    const float* __restrict__ g_in, const float* __restrict__ be_in,
    const float* __restrict__ m_in, const float* __restrict__ v_in,
    const float* __restrict__ g_m, const float* __restrict__ be_m,
    const float* __restrict__ m_m, const float* __restrict__ v_m,
    unsigned short* __restrict__ msgn_b)
{
    __shared__ __align__(16) unsigned short lnb[64 * LNS];
    __shared__ __align__(16) float sc_in[DIN], sh_in[DIN], sc_m[HD], shm2[HD];
    const int t = threadIdx.x;
    const int n0 = blockIdx.x * 64;
    {
        float s = g_in[t] * rsqrtf(v_in[t] + BN_EPS);
        sc_in[t] = s; sh_in[t] = be_in[t] - m_in[t] * s;
        if (t < HD) {
            float s2 = g_m[t] * rsqrtf(v_m[t] + BN_EPS);
            sc_m[t] = s2; shm2[t] = b1[t] * s2 + (be_m[t] - m_m[t] * s2);
        }
    }
    __syncthreads();
    for (int i = t; i < 64 * 64; i += 256) {
        int row = i >> 6, c4 = (i & 63) * 4;
        float4 xx = *(const float4*)(x + (size_t)(n0 + row) * DIN + c4);
        float4 sc = *(const float4*)(sc_in + c4);
        float4 sh = *(const float4*)(sh_in + c4);
        ushort4 o;
        o.x = f2bf(fmaxf(fmaf(xx.x, sc.x, sh.x), 0.f));
        o.y = f2bf(fmaxf(fmaf(xx.y, sc.y, sh.y), 0.f));
        o.z = f2bf(fmaxf(fmaf(xx.z, sc.z, sh.z), 0.f));
        o.w = f2bf(fmaxf(fmaf(xx.w, sc.w, sh.w), 0.f));
        *(ushort4*)(lnb + row * LNS + c4) = o;
    }
    __syncthreads();
    const int w = t >> 6, le = t & 15, g = (t >> 4) & 3;
    const f32x4 zz = {0.f, 0.f, 0.f, 0.f};
    f32x4 acc[4] = {zz, zz, zz, zz};
#pragma unroll
    for (int ks = 0; ks < 8; ++ks) {
        bf16x8 b = *(const bf16x8*)(lnb + (w * 16 + le) * LNS + ks * 32 + g * 8);
#pragma unroll
        for (int jt = 0; jt < 4; ++jt) {
            bf16x8 a = *(const bf16x8*)(w1b + (jt * 16 + le) * 256 + ks * 32 + g * 8);
            acc[jt] = __builtin_amdgcn_mfma_f32_16x16x32_bf16(a, b, acc[jt], 0, 0, 0);
        }
    }
    const int n = n0 + w * 16 + le;
#pragma unroll
    for (int jt = 0; jt < 4; ++jt) {
        int j = jt * 16 + g * 4;
        float4 sc = *(const float4*)(sc_m + j);
        float4 sh = *(const float4*)(shm2 + j);
        ushort4 o;
        o.x = f2bf(fmaxf(fmaf(acc[jt][0], sc.x, sh.x), 0.f));
        o.y = f2bf(fmaxf(fmaf(acc[jt][1], sc.y, sh.y), 0.f));
        o.z = f2bf(fmaxf(fmaf(acc[jt][2], sc.z, sh.z), 0.f));
        o.w = f2bf(fmaxf(fmaf(acc[jt][3], sc.w, sh.w), 0.f));
        *(ushort4*)(msgn_b + (size_t)n * HD + j) = o;
    }
}

// ---------------- kernel B: hid_b = bf16(relu(ei @ kw1 + kb1)) ---------------------------
#define EIS 136
__global__ __launch_bounds__(256) void k_hidden(
    const float* __restrict__ ei, const unsigned short* __restrict__ kw1b,
    const float* __restrict__ kb1, unsigned short* __restrict__ hid_b)
{
    __shared__ __align__(16) unsigned short eib[64 * EIS];
    __shared__ float kb1s[KHD];
    const int t = threadIdx.x;
    const int e0 = blockIdx.x * 64;
    if (t < KHD) kb1s[t] = kb1[t];
    for (int i = t; i < 64 * 32; i += 256) {
        int row = i >> 5, c4 = (i & 31) * 4;
        float4 xx = *(const float4*)(ei + (size_t)(e0 + row) * DE + c4);
        ushort4 o;
        o.x = f2bf(xx.x); o.y = f2bf(xx.y); o.z = f2bf(xx.z); o.w = f2bf(xx.w);
        *(ushort4*)(eib + row * EIS + c4) = o;
    }
    __syncthreads();
    const int w = t >> 6, le = t & 15, g = (t >> 4) & 3;
    const f32x4 zz = {0.f, 0.f, 0.f, 0.f};
    f32x4 acc[2] = {zz, zz};
#pragma unroll
    for (int ks = 0; ks < 4; ++ks) {
        bf16x8 b = *(const bf16x8*)(eib + (w * 16 + le) * EIS + ks * 32 + g * 8);
#pragma unroll
        for (int jt = 0; jt < 2; ++jt) {
            bf16x8 a = *(const bf16x8*)(kw1b + (jt * 16 + le) * 128 + ks * 32 + g * 8);
            acc[jt] = __builtin_amdgcn_mfma_f32_16x16x32_bf16(a, b, acc[jt], 0, 0, 0);
        }
    }
    const int e = e0 + w * 16 + le;
#pragma unroll
    for (int jt = 0; jt < 2; ++jt) {
        int h = jt * 16 + g * 4;
        ushort4 o;
        o.x = f2bf(fmaxf(acc[jt][0] + kb1s[h + 0], 0.f));
        o.y = f2bf(fmaxf(acc[jt][1] + kb1s[h + 1], 0.f));
        o.z = f2bf(fmaxf(acc[jt][2] + kb1s[h + 2], 0.f));
        o.w = f2bf(fmaxf(acc[jt][3] + kb1s[h + 3], 0.f));
        *(ushort4*)(hid_b + (size_t)e * KHD + h) = o;
    }
}

// ---------------- CSR build --------------------------------------------------------------
__global__ __launch_bounds__(256) void k_deg(const int* __restrict__ elist, int* __restrict__ deg) {
    int e = blockIdx.x * 256 + threadIdx.x;
    if (e < NE) atomicAdd(&deg[elist[(size_t)e * 2 + 1]], 1);
}

__global__ __launch_bounds__(1024) void k_scan(const int* __restrict__ deg,
                                               int* __restrict__ rowptr, int* __restrict__ cursor) {
    __shared__ int part[1024];
    const int t = threadIdx.x;
    const int base = t * 16;
    int loc[16]; int s = 0;
#pragma unroll
    for (int i = 0; i < 16; ++i) {
        int idx = base + i;
        int v = (idx < NN) ? deg[idx] : 0;
        loc[i] = s; s += v;
    }
    part[t] = s;
    __syncthreads();
    for (int off = 1; off < 1024; off <<= 1) {
        int v = (t >= off) ? part[t - off] : 0;
        __syncthreads();
        part[t] += v;
        __syncthreads();
    }
    int pre = (t == 0) ? 0 : part[t - 1];
#pragma unroll
    for (int i = 0; i < 16; ++i) {
        int idx = base + i;
        if (idx < NN) { rowptr[idx] = pre + loc[i]; cursor[idx] = pre + loc[i]; }
    }
    if (t == 1023) rowptr[NN] = part[1023];
}

__global__ __launch_bounds__(256) void k_place(const int* __restrict__ elist,
                                               int* __restrict__ cursor, int* __restrict__ epos) {
    int e = blockIdx.x * 256 + threadIdx.x;
    if (e < NE) {
        int n = elist[(size_t)e * 2 + 1];
        epos[e] = atomicAdd(&cursor[n], 1);
    }
}

// ---------------- kernel D: fused bilinear via MFMA (64 edges/block, 8 waves) ------------
// Same math/indexing as the proven round-5 kernel; wave decomposition changed:
// wave w: j-tile = (w&3)*16, e-half = (w>>2)*32; each wave does 16j x 32e (nt=0..1).
#define HS 36
__global__ __launch_bounds__(512) void k_edge(
    const unsigned short* __restrict__ msgn_b,   // [NN][64]
    const unsigned short* __restrict__ hid_b,    // [NE][32]
    const int* __restrict__ elist, const float* __restrict__ eweight,
    const int* __restrict__ epos,
    const unsigned short* __restrict__ Wb,       // [33][64][64]
    const unsigned short* __restrict__ W0b,      // [64][32]
    const float* __restrict__ kb2,
    unsigned short* __restrict__ msg_out)        // [NE][64] bf16, CSR-permuted, *eweight
{
    __shared__ __align__(16) float hids[64 * HS];
    const int t = threadIdx.x;
    const int w = t >> 6, le = t & 15, g = (t >> 4) & 3;
    const int wjt = w & 3;    // j-tile 0..3
    const int eh  = w >> 2;   // e-half 0..1
    const int e0 = blockIdx.x * 64;

    {   // stage hid (64 edges x 32 h) as f32 into LDS; 512 threads cover it exactly
        int e = t >> 3, h4 = (t & 7) * 4;
        ushort4 hh = *(const ushort4*)(hid_b + (size_t)(e0 + e) * KHD + h4);
        float4 f; f.x = bf2f(hh.x); f.y = bf2f(hh.y); f.z = bf2f(hh.z); f.w = bf2f(hh.w);
        *(float4*)(hids + e * HS + h4) = f;
    }
    if (t < 64) hids[t * HS + 32] = 1.0f;

    int eid[2], ep[2];
#pragma unroll
    for (int nt = 0; nt < 2; ++nt) {
        eid[nt] = e0 + eh * 32 + nt * 16 + le;
        ep[nt] = epos[eid[nt]];
    }

    bf16x8 bm[2][2];
#pragma unroll
    for (int nt = 0; nt < 2; ++nt) {
        int ni = elist[(size_t)eid[nt] * 2];
#pragma unroll
        for (int ks = 0; ks < 2; ++ks)
            bm[nt][ks] = *(const bf16x8*)(msgn_b + (size_t)ni * HD + ks * 32 + g * 8);
    }

    const f32x4 zz = {0.f, 0.f, 0.f, 0.f};
    f32x4 acc[2];
    {   // r=0 block: A[j][h]=kw2[h,j], B=hid (bf16), K=32
        bf16x8 a0 = *(const bf16x8*)(W0b + (wjt * 16 + le) * KHD + g * 8);
#pragma unroll
        for (int nt = 0; nt < 2; ++nt) {
            bf16x8 hb = *(const bf16x8*)(hid_b + (size_t)eid[nt] * KHD + g * 8);
            acc[nt] = __builtin_amdgcn_mfma_f32_16x16x32_bf16(a0, hb, zz, 0, 0, 0);
        }
    }
    __syncthreads();

#pragma unroll 3
    for (int h = 0; h < 33; ++h) {
        float hv[2];
#pragma unroll
        for (int nt = 0; nt < 2; ++nt) hv[nt] = hids[(eh * 32 + nt * 16 + le) * HS + h];
        const unsigned short* wh = Wb + (size_t)h * 4096 + (wjt * 16 + le) * 64;
        bf16x8 a0 = *(const bf16x8*)(wh + g * 8);
        bf16x8 a1 = *(const bf16x8*)(wh + 32 + g * 8);
#pragma unroll
        for (int nt = 0; nt < 2; ++nt) {
            f32x4 c = __builtin_amdgcn_mfma_f32_16x16x32_bf16(a0, bm[nt][0], zz, 0, 0, 0);
            c = __builtin_amdgcn_mfma_f32_16x16x32_bf16(a1, bm[nt][1], c, 0, 0, 0);
            acc[nt] += hv[nt] * c;
        }
    }

    const int j = wjt * 16 + g * 4;
    float4 kbv = *(const float4*)(kb2 + j);
#pragma unroll
    for (int nt = 0; nt < 2; ++nt) {
        float ew = eweight[eid[nt]];
        ushort4 o;
        o.x = f2bf((acc[nt][0] + kbv.x) * ew);
        o.y = f2bf((acc[nt][1] + kbv.y) * ew);
        o.z = f2bf((acc[nt][2] + kbv.z) * ew);
        o.w = f2bf((acc[nt][3] + kbv.w) * ew);
        *(ushort4*)(msg_out + (size_t)ep[nt] * HD + j) = o;
    }
}

// ---------------- kernel E: streaming segment-sum + bn_upd/relu + MFMA GEMM + bn_out -----
#define UTS 72
__global__ __launch_bounds__(256) void k_out(
    const unsigned short* __restrict__ msg_out,  // CSR-ordered
    const int* __restrict__ rowptr,
    const unsigned short* __restrict__ w2b, const float* __restrict__ b2,
    const float* __restrict__ g_u, const float* __restrict__ be_u,
    const float* __restrict__ m_u, const float* __restrict__ v_u,
    const float* __restrict__ g_o, const float* __restrict__ be_o,
    const float* __restrict__ m_o, const float* __restrict__ v_o,
    float* __restrict__ out)
{
    __shared__ __align__(16) unsigned short utb[64 * UTS];
    __shared__ __align__(16) float sc_o[DOUT], sho2[DOUT], sc_u[HD], sh_u[HD];
    const int t = threadIdx.x;
    const int n0 = blockIdx.x * 64;
    {
        float s = g_o[t] * rsqrtf(v_o[t] + BN_EPS);
        sc_o[t] = s; sho2[t] = b2[t] * s + (be_o[t] - m_o[t] * s);
        if (t < HD) {
            float s2 = g_u[t] * rsqrtf(v_u[t] + BN_EPS);
            sc_u[t] = s2; sh_u[t] = be_u[t] - m_u[t] * s2;
        }
    }
    __syncthreads();
    {
        const int j = t & 63, qw = t >> 6;
        for (int r = qw; r < 64; r += 4) {
            int n = n0 + r;
            int p0 = rowptr[n], p1 = rowptr[n + 1];
            float a = 0.f;
            for (int p = p0; p < p1; ++p)
                a += bf2f(msg_out[(size_t)p * HD + j]);
            utb[r * UTS + j] = f2bf(fmaxf(fmaf(a, sc_u[j], sh_u[j]), 0.f));
        }
    }
    __syncthreads();
    const int w = t >> 6, le = t & 15, g = (t >> 4) & 3;
    const f32x4 zz = {0.f, 0.f, 0.f, 0.f};
    f32x4 acc[4][4];
#pragma unroll
    for (int jt = 0; jt < 4; ++jt)
#pragma unroll
        for (int nt = 0; nt < 4; ++nt) acc[jt][nt] = zz;
#pragma unroll
    for (int ks = 0; ks < 2; ++ks) {
        bf16x8 b[4];
#pragma unroll
        for (int nt = 0; nt < 4; ++nt)
            b[nt] = *(const bf16x8*)(utb + (nt * 16 + le) * UTS + ks * 32 + g * 8);
#pragma unroll
        for (int jt = 0; jt < 4; ++jt) {
            bf16x8 a = *(const bf16x8*)(w2b + (size_t)(w * 64 + jt * 16 + le) * HD + ks * 32 + g * 8);
#pragma unroll
            for (int nt = 0; nt < 4; ++nt)
                acc[jt][nt] = __builtin_amdgcn_mfma_f32_16x16x32_bf16(a, b[nt], acc[jt][nt], 0, 0, 0);
        }
    }
#pragma unroll
    for (int jt = 0; jt < 4; ++jt) {
        int c = w * 64 + jt * 16 + g * 4;
        float4 sc = *(const float4*)(sc_o + c);
        float4 sh = *(const float4*)(sho2 + c);
#pragma unroll
        for (int nt = 0; nt < 4; ++nt) {
            int n = n0 + nt * 16 + le;
            float4 o;
            o.x = fmaf(acc[jt][nt][0], sc.x, sh.x);
            o.y = fmaf(acc[jt][nt][1], sc.y, sh.y);
            o.z = fmaf(acc[jt][nt][2], sc.z, sh.z);
            o.w = fmaf(acc[jt][nt][3], sc.w, sh.w);
            *(float4*)(out + (size_t)n * DOUT + c) = o;
        }
    }
}

extern "C" void kernel_launch(void* const* d_in, const int* in_sizes, int n_in,
                              void* d_out, int out_size, void* d_ws, size_t ws_size,
                              hipStream_t stream)
{
    (void)in_sizes; (void)n_in; (void)out_size; (void)ws_size;
    const float* x    = (const float*)d_in[0];
    const float* ei   = (const float*)d_in[1];
    const int*   el   = (const int*)  d_in[2];
    const float* ew   = (const float*)d_in[3];
    const float* w1   = (const float*)d_in[4];
    const float* b1   = (const float*)d_in[5];
    const float* kw1  = (const float*)d_in[6];
    const float* kb1  = (const float*)d_in[7];
    const float* kw2  = (const float*)d_in[8];
    const float* kb2  = (const float*)d_in[9];
    const float* w2   = (const float*)d_in[10];
    const float* b2   = (const float*)d_in[11];
    const float* g_in = (const float*)d_in[12], *be_in = (const float*)d_in[13];
    const float* m_in = (const float*)d_in[14], *v_in  = (const float*)d_in[15];
    const float* g_m  = (const float*)d_in[16], *be_m  = (const float*)d_in[17];
    const float* m_m  = (const float*)d_in[18], *v_m   = (const float*)d_in[19];
    const float* g_u  = (const float*)d_in[20], *be_u  = (const float*)d_in[21];
    const float* m_u  = (const float*)d_in[22], *v_u   = (const float*)d_in[23];
    const float* g_o  = (const float*)d_in[24], *be_o  = (const float*)d_in[25];
    const float* m_o  = (const float*)d_in[26], *v_o   = (const float*)d_in[27];

    char* wsb = (char*)d_ws;
    size_t off = 0;
    auto alloc = [&](size_t bytes) -> void* {
        void* p = wsb + off; off += (bytes + 255) & ~(size_t)255; return p;
    };
    unsigned short* msgn_b  = (unsigned short*)alloc((size_t)NN * HD * 2);
    unsigned short* hid_b   = (unsigned short*)alloc((size_t)NE * KHD * 2);
    unsigned short* Wb      = (unsigned short*)alloc((size_t)33 * 4096 * 2);
    unsigned short* W0b     = (unsigned short*)alloc((size_t)64 * KHD * 2);
    unsigned short* w1b     = (unsigned short*)alloc((size_t)HD * DIN * 2);
    unsigned short* kw1b    = (unsigned short*)alloc((size_t)KHD * DE * 2);
    unsigned short* w2b     = (unsigned short*)alloc((size_t)DOUT * HD * 2);
    int* rowptr = (int*)alloc((size_t)(NN + 1) * 4);
    int* epos   = (int*)alloc((size_t)NE * 4);
    // union: deg+cursor live only until k_place; msg_out written after (k_edge)
    char* un = (char*)alloc((size_t)NE * HD * 2);
    unsigned short* msg_out = (unsigned short*)un;
    int* deg    = (int*)un;
    int* cursor = (int*)(un + (((size_t)NN * 4 + 255) & ~(size_t)255));

    hipMemsetAsync(deg, 0, (size_t)NN * 4, stream);
    hipLaunchKernelGGL(k_prep, dim3(680), dim3(256), 0, stream,
                       kw2, kb2, w1, kw1, w2, Wb, W0b, w1b, kw1b, w2b);
    hipLaunchKernelGGL(k_deg, dim3(NE / 256), dim3(256), 0, stream, el, deg);
    hipLaunchKernelGGL(k_scan, dim3(1), dim3(1024), 0, stream, deg, rowptr, cursor);
    hipLaunchKernelGGL(k_place, dim3(NE / 256), dim3(256), 0, stream, el, cursor, epos);
    hipLaunchKernelGGL(k_msgn, dim3(NN / 64), dim3(256), 0, stream,
                       x, w1b, b1, g_in, be_in, m_in, v_in, g_m, be_m, m_m, v_m, msgn_b);
    hipLaunchKernelGGL(k_hidden, dim3(NE / 64), dim3(256), 0, stream,
                       ei, kw1b, kb1, hid_b);
    hipLaunchKernelGGL(k_edge, dim3(NE / 64), dim3(512), 0, stream,
                       msgn_b, hid_b, el, ew, epos, Wb, W0b, kb2, msg_out);
    hipLaunchKernelGGL(k_out, dim3(NN / 64), dim3(256), 0, stream,
                       msg_out, rowptr, w2b, b2, g_u, be_u, m_u, v_u,
                       g_o, be_o, m_o, v_o, (float*)d_out);
}

// Round 7
// 137.684 us; speedup vs baseline: 1.1960x; 1.1960x over previous
//
#include <hip/hip_runtime.h>

#define NN   16000
#define NE   64000
#define DIN  256
#define HD   64
#define DOUT 256
#define DE   128
#define KHD  32
#define BN_EPS 1e-5f

typedef __attribute__((ext_vector_type(8))) short bf16x8;
typedef __attribute__((ext_vector_type(4))) float f32x4;

__device__ __forceinline__ unsigned short f2bf(float f) {
    unsigned int u = __float_as_uint(f);
    u += 0x7fff + ((u >> 16) & 1);
    return (unsigned short)(u >> 16);
}
__device__ __forceinline__ float bf2f(unsigned short s) {
    return __uint_as_float(((unsigned int)s) << 16);
}

// ---------------- kernel P: pack all weights into bf16 MFMA layouts ----------------------
__global__ __launch_bounds__(256) void k_prep(
    const float* __restrict__ kw2, const float* __restrict__ kb2,
    const float* __restrict__ w1, const float* __restrict__ kw1, const float* __restrict__ w2,
    unsigned short* __restrict__ Wb, unsigned short* __restrict__ W0b,
    unsigned short* __restrict__ w1b, unsigned short* __restrict__ kw1b,
    unsigned short* __restrict__ w2b)
{
    int idx = blockIdx.x * 256 + threadIdx.x;
    if (idx < 33 * 4096) {
        int h = idx >> 12, r = idx & 4095;
        float v = (h < 32) ? kw2[(size_t)h * 4160 + 64 + r] : kb2[64 + r];
        Wb[idx] = f2bf(v);
        return;
    }
    idx -= 33 * 4096;
    if (idx < 2048) { int j = idx >> 5, h = idx & 31; W0b[idx] = f2bf(kw2[(size_t)h * 4160 + j]); return; }
    idx -= 2048;
    if (idx < 16384) { int j = idx >> 8, k = idx & 255; w1b[idx] = f2bf(w1[(size_t)k * 64 + j]); return; }
    idx -= 16384;
    if (idx < 4096) { int h = idx >> 7, k = idx & 127; kw1b[idx] = f2bf(kw1[(size_t)k * 32 + h]); return; }
    idx -= 4096;
    if (idx < 16384) { int c = idx >> 6, k = idx & 63; w2b[idx] = f2bf(w2[(size_t)k * 256 + c]); return; }
}

// ---------------- kernel A: msgn_b = bf16(relu(bn_msg(relu(bn_in(x)) @ w1 + b1))) --------
#define LNS 264
__global__ __launch_bounds__(256) void k_msgn(
    const float* __restrict__ x, const unsigned short* __restrict__ w1b,
    const float* __restrict__ b1,
    const float* __restrict__ g_in, const float* __restrict__ be_in,
    const float* __restrict__ m_in, const float* __restrict__ v_in,
    const float* __restrict__ g_m, const float* __restrict__ be_m,
    const float* __restrict__ m_m, const float* __restrict__ v_m,
    unsigned short* __restrict__ msgn_b)
{
    __shared__ __align__(16) unsigned short lnb[64 * LNS];
    __shared__ __align__(16) float sc_in[DIN], sh_in[DIN], sc_m[HD], shm2[HD];
    const int t = threadIdx.x;
    const int n0 = blockIdx.x * 64;
    {
        float s = g_in[t] * rsqrtf(v_in[t] + BN_EPS);
        sc_in[t] = s; sh_in[t] = be_in[t] - m_in[t] * s;
        if (t < HD) {
            float s2 = g_m[t] * rsqrtf(v_m[t] + BN_EPS);
            sc_m[t] = s2; shm2[t] = b1[t] * s2 + (be_m[t] - m_m[t] * s2);
        }
    }
    __syncthreads();
    for (int i = t; i < 64 * 64; i += 256) {
        int row = i >> 6, c4 = (i & 63) * 4;
        float4 xx = *(const float4*)(x + (size_t)(n0 + row) * DIN + c4);
        float4 sc = *(const float4*)(sc_in + c4);
        float4 sh = *(const float4*)(sh_in + c4);
        ushort4 o;
        o.x = f2bf(fmaxf(fmaf(xx.x, sc.x, sh.x), 0.f));
        o.y = f2bf(fmaxf(fmaf(xx.y, sc.y, sh.y), 0.f));
        o.z = f2bf(fmaxf(fmaf(xx.z, sc.z, sh.z), 0.f));
        o.w = f2bf(fmaxf(fmaf(xx.w, sc.w, sh.w), 0.f));
        *(ushort4*)(lnb + row * LNS + c4) = o;
    }
    __syncthreads();
    const int w = t >> 6, le = t & 15, g = (t >> 4) & 3;
    const f32x4 zz = {0.f, 0.f, 0.f, 0.f};
    f32x4 acc[4] = {zz, zz, zz, zz};
#pragma unroll
    for (int ks = 0; ks < 8; ++ks) {
        bf16x8 b = *(const bf16x8*)(lnb + (w * 16 + le) * LNS + ks * 32 + g * 8);
#pragma unroll
        for (int jt = 0; jt < 4; ++jt) {
            bf16x8 a = *(const bf16x8*)(w1b + (jt * 16 + le) * 256 + ks * 32 + g * 8);
            acc[jt] = __builtin_amdgcn_mfma_f32_16x16x32_bf16(a, b, acc[jt], 0, 0, 0);
        }
    }
    const int n = n0 + w * 16 + le;
#pragma unroll
    for (int jt = 0; jt < 4; ++jt) {
        int j = jt * 16 + g * 4;
        float4 sc = *(const float4*)(sc_m + j);
        float4 sh = *(const float4*)(shm2 + j);
        ushort4 o;
        o.x = f2bf(fmaxf(fmaf(acc[jt][0], sc.x, sh.x), 0.f));
        o.y = f2bf(fmaxf(fmaf(acc[jt][1], sc.y, sh.y), 0.f));
        o.z = f2bf(fmaxf(fmaf(acc[jt][2], sc.z, sh.z), 0.f));
        o.w = f2bf(fmaxf(fmaf(acc[jt][3], sc.w, sh.w), 0.f));
        *(ushort4*)(msgn_b + (size_t)n * HD + j) = o;
    }
}

// ---------------- kernel B: hid_b = bf16(relu(ei @ kw1 + kb1)) ---------------------------
#define EIS 136
__global__ __launch_bounds__(256) void k_hidden(
    const float* __restrict__ ei, const unsigned short* __restrict__ kw1b,
    const float* __restrict__ kb1, unsigned short* __restrict__ hid_b)
{
    __shared__ __align__(16) unsigned short eib[64 * EIS];
    __shared__ float kb1s[KHD];
    const int t = threadIdx.x;
    const int e0 = blockIdx.x * 64;
    if (t < KHD) kb1s[t] = kb1[t];
    for (int i = t; i < 64 * 32; i += 256) {
        int row = i >> 5, c4 = (i & 31) * 4;
        float4 xx = *(const float4*)(ei + (size_t)(e0 + row) * DE + c4);
        ushort4 o;
        o.x = f2bf(xx.x); o.y = f2bf(xx.y); o.z = f2bf(xx.z); o.w = f2bf(xx.w);
        *(ushort4*)(eib + row * EIS + c4) = o;
    }
    __syncthreads();
    const int w = t >> 6, le = t & 15, g = (t >> 4) & 3;
    const f32x4 zz = {0.f, 0.f, 0.f, 0.f};
    f32x4 acc[2] = {zz, zz};
#pragma unroll
    for (int ks = 0; ks < 4; ++ks) {
        bf16x8 b = *(const bf16x8*)(eib + (w * 16 + le) * EIS + ks * 32 + g * 8);
#pragma unroll
        for (int jt = 0; jt < 2; ++jt) {
            bf16x8 a = *(const bf16x8*)(kw1b + (jt * 16 + le) * 128 + ks * 32 + g * 8);
            acc[jt] = __builtin_amdgcn_mfma_f32_16x16x32_bf16(a, b, acc[jt], 0, 0, 0);
        }
    }
    const int e = e0 + w * 16 + le;
#pragma unroll
    for (int jt = 0; jt < 2; ++jt) {
        int h = jt * 16 + g * 4;
        ushort4 o;
        o.x = f2bf(fmaxf(acc[jt][0] + kb1s[h + 0], 0.f));
        o.y = f2bf(fmaxf(acc[jt][1] + kb1s[h + 1], 0.f));
        o.z = f2bf(fmaxf(acc[jt][2] + kb1s[h + 2], 0.f));
        o.w = f2bf(fmaxf(acc[jt][3] + kb1s[h + 3], 0.f));
        *(ushort4*)(hid_b + (size_t)e * KHD + h) = o;
    }
}

// ---------------- CSR build --------------------------------------------------------------
__global__ __launch_bounds__(256) void k_deg(const int* __restrict__ elist, int* __restrict__ deg) {
    int e = blockIdx.x * 256 + threadIdx.x;
    if (e < NE) atomicAdd(&deg[elist[(size_t)e * 2 + 1]], 1);
}

__global__ __launch_bounds__(1024) void k_scan(const int* __restrict__ deg,
                                               int* __restrict__ rowptr, int* __restrict__ cursor) {
    __shared__ int part[1024];
    const int t = threadIdx.x;
    const int base = t * 16;
    int loc[16]; int s = 0;
#pragma unroll
    for (int i = 0; i < 16; ++i) {
        int idx = base + i;
        int v = (idx < NN) ? deg[idx] : 0;
        loc[i] = s; s += v;
    }
    part[t] = s;
    __syncthreads();
    for (int off = 1; off < 1024; off <<= 1) {
        int v = (t >= off) ? part[t - off] : 0;
        __syncthreads();
        part[t] += v;
        __syncthreads();
    }
    int pre = (t == 0) ? 0 : part[t - 1];
#pragma unroll
    for (int i = 0; i < 16; ++i) {
        int idx = base + i;
        if (idx < NN) { rowptr[idx] = pre + loc[i]; cursor[idx] = pre + loc[i]; }
    }
    if (t == 1023) rowptr[NN] = part[1023];
}

__global__ __launch_bounds__(256) void k_place(const int* __restrict__ elist,
                                               int* __restrict__ cursor, int* __restrict__ epos) {
    int e = blockIdx.x * 256 + threadIdx.x;
    if (e < NE) {
        int n = elist[(size_t)e * 2 + 1];
        epos[e] = atomicAdd(&cursor[n], 1);
    }
}

// ---------------- kernel D: fused bilinear via MFMA (64 edges/block, 4 waves) ------------
// Round-5 proven structure + distance-2 register prefetch of the Wb A-fragments.
// NOTE: prefetch reads rows h=33,34 of Wb -> lands in the adjacent W0b/w1b ws
// allocations (in-bounds, values never consumed).
#define HS 36
__global__ __launch_bounds__(256) void k_edge(
    const unsigned short* __restrict__ msgn_b,   // [NN][64]
    const unsigned short* __restrict__ hid_b,    // [NE][32]
    const int* __restrict__ elist, const float* __restrict__ eweight,
    const int* __restrict__ epos,
    const unsigned short* __restrict__ Wb,       // [33][64][64]
    const unsigned short* __restrict__ W0b,      // [64][32]
    const float* __restrict__ kb2,
    unsigned short* __restrict__ msg_out)        // [NE][64] bf16, CSR-permuted, *eweight
{
    __shared__ __align__(16) float hids[64 * HS];
    const int t = threadIdx.x;
    const int w = t >> 6, le = t & 15, g = (t >> 4) & 3;
    const int e0 = blockIdx.x * 64;

    for (int q = t; q < 512; q += 256) {
        int e = q >> 3, h4 = (q & 7) * 4;
        ushort4 hh = *(const ushort4*)(hid_b + (size_t)(e0 + e) * KHD + h4);
        float4 f; f.x = bf2f(hh.x); f.y = bf2f(hh.y); f.z = bf2f(hh.z); f.w = bf2f(hh.w);
        *(float4*)(hids + e * HS + h4) = f;
    }
    if (t < 64) hids[t * HS + 32] = 1.0f;

    int eid[4], ep[4];
#pragma unroll
    for (int nt = 0; nt < 4; ++nt) {
        eid[nt] = e0 + nt * 16 + le;
        ep[nt] = epos[eid[nt]];
    }

    bf16x8 bm[4][2];
#pragma unroll
    for (int nt = 0; nt < 4; ++nt) {
        int ni = elist[(size_t)eid[nt] * 2];
#pragma unroll
        for (int ks = 0; ks < 2; ++ks)
            bm[nt][ks] = *(const bf16x8*)(msgn_b + (size_t)ni * HD + ks * 32 + g * 8);
    }

    const f32x4 zz = {0.f, 0.f, 0.f, 0.f};
    f32x4 acc[4];
    {   // r=0 block: A[j][h]=kw2[h,j], B=hid (bf16), K=32
        bf16x8 a0 = *(const bf16x8*)(W0b + (w * 16 + le) * KHD + g * 8);
#pragma unroll
        for (int nt = 0; nt < 4; ++nt) {
            bf16x8 hb = *(const bf16x8*)(hid_b + (size_t)eid[nt] * KHD + g * 8);
            acc[nt] = __builtin_amdgcn_mfma_f32_16x16x32_bf16(a0, hb, zz, 0, 0, 0);
        }
    }
    __syncthreads();

    // ---- h-loop with distance-2 A-fragment prefetch ----
    const unsigned short* wbase = Wb + (size_t)(w * 16 + le) * 64 + g * 8;
    bf16x8 a0c = *(const bf16x8*)(wbase);                 // h = 0
    bf16x8 a1c = *(const bf16x8*)(wbase + 32);
    bf16x8 a0q = *(const bf16x8*)(wbase + 4096);          // h = 1
    bf16x8 a1q = *(const bf16x8*)(wbase + 4096 + 32);
#pragma unroll 3
    for (int h = 0; h < 33; ++h) {
        bf16x8 a0n = *(const bf16x8*)(wbase + (size_t)(h + 2) * 4096);
        bf16x8 a1n = *(const bf16x8*)(wbase + (size_t)(h + 2) * 4096 + 32);
        float hv[4];
#pragma unroll
        for (int nt = 0; nt < 4; ++nt) hv[nt] = hids[(nt * 16 + le) * HS + h];
#pragma unroll
        for (int nt = 0; nt < 4; ++nt) {
            f32x4 c = __builtin_amdgcn_mfma_f32_16x16x32_bf16(a0c, bm[nt][0], zz, 0, 0, 0);
            c = __builtin_amdgcn_mfma_f32_16x16x32_bf16(a1c, bm[nt][1], c, 0, 0, 0);
            acc[nt] += hv[nt] * c;
        }
        a0c = a0q; a1c = a1q; a0q = a0n; a1q = a1n;
    }

    const int j = w * 16 + g * 4;
    float4 kbv = *(const float4*)(kb2 + j);
#pragma unroll
    for (int nt = 0; nt < 4; ++nt) {
        float ew = eweight[eid[nt]];
        ushort4 o;
        o.x = f2bf((acc[nt][0] + kbv.x) * ew);
        o.y = f2bf((acc[nt][1] + kbv.y) * ew);
        o.z = f2bf((acc[nt][2] + kbv.z) * ew);
        o.w = f2bf((acc[nt][3] + kbv.w) * ew);
        *(ushort4*)(msg_out + (size_t)ep[nt] * HD + j) = o;
    }
}

// ---------------- kernel E: streaming segment-sum + bn_upd/relu + MFMA GEMM + bn_out -----
#define UTS 72
__global__ __launch_bounds__(256) void k_out(
    const unsigned short* __restrict__ msg_out,  // CSR-ordered
    const int* __restrict__ rowptr,
    const unsigned short* __restrict__ w2b, const float* __restrict__ b2,
    const float* __restrict__ g_u, const float* __restrict__ be_u,
    const float* __restrict__ m_u, const float* __restrict__ v_u,
    const float* __restrict__ g_o, const float* __restrict__ be_o,
    const float* __restrict__ m_o, const float* __restrict__ v_o,
    float* __restrict__ out)
{
    __shared__ __align__(16) unsigned short utb[64 * UTS];
    __shared__ __align__(16) float sc_o[DOUT], sho2[DOUT], sc_u[HD], sh_u[HD];
    const int t = threadIdx.x;
    const int n0 = blockIdx.x * 64;
    {
        float s = g_o[t] * rsqrtf(v_o[t] + BN_EPS);
        sc_o[t] = s; sho2[t] = b2[t] * s + (be_o[t] - m_o[t] * s);
        if (t < HD) {
            float s2 = g_u[t] * rsqrtf(v_u[t] + BN_EPS);
            sc_u[t] = s2; sh_u[t] = be_u[t] - m_u[t] * s2;
        }
    }
    __syncthreads();
    {
        const int j = t & 63, qw = t >> 6;
        for (int r = qw; r < 64; r += 4) {
            int n = n0 + r;
            int p0 = rowptr[n], p1 = rowptr[n + 1];
            float a = 0.f;
            for (int p = p0; p < p1; ++p)
                a += bf2f(msg_out[(size_t)p * HD + j]);
            utb[r * UTS + j] = f2bf(fmaxf(fmaf(a, sc_u[j], sh_u[j]), 0.f));
        }
    }
    __syncthreads();
    const int w = t >> 6, le = t & 15, g = (t >> 4) & 3;
    const f32x4 zz = {0.f, 0.f, 0.f, 0.f};
    f32x4 acc[4][4];
#pragma unroll
    for (int jt = 0; jt < 4; ++jt)
#pragma unroll
        for (int nt = 0; nt < 4; ++nt) acc[jt][nt] = zz;
#pragma unroll
    for (int ks = 0; ks < 2; ++ks) {
        bf16x8 b[4];
#pragma unroll
        for (int nt = 0; nt < 4; ++nt)
            b[nt] = *(const bf16x8*)(utb + (nt * 16 + le) * UTS + ks * 32 + g * 8);
#pragma unroll
        for (int jt = 0; jt < 4; ++jt) {
            bf16x8 a = *(const bf16x8*)(w2b + (size_t)(w * 64 + jt * 16 + le) * HD + ks * 32 + g * 8);
#pragma unroll
            for (int nt = 0; nt < 4; ++nt)
                acc[jt][nt] = __builtin_amdgcn_mfma_f32_16x16x32_bf16(a, b[nt], acc[jt][nt], 0, 0, 0);
        }
    }
#pragma unroll
    for (int jt = 0; jt < 4; ++jt) {
        int c = w * 64 + jt * 16 + g * 4;
        float4 sc = *(const float4*)(sc_o + c);
        float4 sh = *(const float4*)(sho2 + c);
#pragma unroll
        for (int nt = 0; nt < 4; ++nt) {
            int n = n0 + nt * 16 + le;
            float4 o;
            o.x = fmaf(acc[jt][nt][0], sc.x, sh.x);
            o.y = fmaf(acc[jt][nt][1], sc.y, sh.y);
            o.z = fmaf(acc[jt][nt][2], sc.z, sh.z);
            o.w = fmaf(acc[jt][nt][3], sc.w, sh.w);
            *(float4*)(out + (size_t)n * DOUT + c) = o;
        }
    }
}

extern "C" void kernel_launch(void* const* d_in, const int* in_sizes, int n_in,
                              void* d_out, int out_size, void* d_ws, size_t ws_size,
                              hipStream_t stream)
{
    (void)in_sizes; (void)n_in; (void)out_size; (void)ws_size;
    const float* x    = (const float*)d_in[0];
    const float* ei   = (const float*)d_in[1];
    const int*   el   = (const int*)  d_in[2];
    const float* ew   = (const float*)d_in[3];
    const float* w1   = (const float*)d_in[4];
    const float* b1   = (const float*)d_in[5];
    const float* kw1  = (const float*)d_in[6];
    const float* kb1  = (const float*)d_in[7];
    const float* kw2  = (const float*)d_in[8];
    const float* kb2  = (const float*)d_in[9];
    const float* w2   = (const float*)d_in[10];
    const float* b2   = (const float*)d_in[11];
    const float* g_in = (const float*)d_in[12], *be_in = (const float*)d_in[13];
    const float* m_in = (const float*)d_in[14], *v_in  = (const float*)d_in[15];
    const float* g_m  = (const float*)d_in[16], *be_m  = (const float*)d_in[17];
    const float* m_m  = (const float*)d_in[18], *v_m   = (const float*)d_in[19];
    const float* g_u  = (const float*)d_in[20], *be_u  = (const float*)d_in[21];
    const float* m_u  = (const float*)d_in[22], *v_u   = (const float*)d_in[23];
    const float* g_o  = (const float*)d_in[24], *be_o  = (const float*)d_in[25];
    const float* m_o  = (const float*)d_in[26], *v_o   = (const float*)d_in[27];

    char* wsb = (char*)d_ws;
    size_t off = 0;
    auto alloc = [&](size_t bytes) -> void* {
        void* p = wsb + off; off += (bytes + 255) & ~(size_t)255; return p;
    };
    unsigned short* msgn_b  = (unsigned short*)alloc((size_t)NN * HD * 2);
    unsigned short* hid_b   = (unsigned short*)alloc((size_t)NE * KHD * 2);
    unsigned short* Wb      = (unsigned short*)alloc((size_t)33 * 4096 * 2);
    unsigned short* W0b     = (unsigned short*)alloc((size_t)64 * KHD * 2);
    unsigned short* w1b     = (unsigned short*)alloc((size_t)HD * DIN * 2);
    unsigned short* kw1b    = (unsigned short*)alloc((size_t)KHD * DE * 2);
    unsigned short* w2b     = (unsigned short*)alloc((size_t)DOUT * HD * 2);
    int* rowptr = (int*)alloc((size_t)(NN + 1) * 4);
    int* epos   = (int*)alloc((size_t)NE * 4);
    // union: deg+cursor live only until k_place; msg_out written after (k_edge)
    char* un = (char*)alloc((size_t)NE * HD * 2);
    unsigned short* msg_out = (unsigned short*)un;
    int* deg    = (int*)un;
    int* cursor = (int*)(un + (((size_t)NN * 4 + 255) & ~(size_t)255));

    hipMemsetAsync(deg, 0, (size_t)NN * 4, stream);
    hipLaunchKernelGGL(k_prep, dim3(680), dim3(256), 0, stream,
                       kw2, kb2, w1, kw1, w2, Wb, W0b, w1b, kw1b, w2b);
    hipLaunchKernelGGL(k_deg, dim3(NE / 256), dim3(256), 0, stream, el, deg);
    hipLaunchKernelGGL(k_scan, dim3(1), dim3(1024), 0, stream, deg, rowptr, cursor);
    hipLaunchKernelGGL(k_place, dim3(NE / 256), dim3(256), 0, stream, el, cursor, epos);
    hipLaunchKernelGGL(k_msgn, dim3(NN / 64), dim3(256), 0, stream,
                       x, w1b, b1, g_in, be_in, m_in, v_in, g_m, be_m, m_m, v_m, msgn_b);
    hipLaunchKernelGGL(k_hidden, dim3(NE / 64), dim3(256), 0, stream,
                       ei, kw1b, kb1, hid_b);
    hipLaunchKernelGGL(k_edge, dim3(NE / 64), dim3(256), 0, stream,
                       msgn_b, hid_b, el, ew, epos, Wb, W0b, kb2, msg_out);
    hipLaunchKernelGGL(k_out, dim3(NN / 64), dim3(256), 0, stream,
                       msg_out, rowptr, w2b, b2, g_u, be_u, m_u, v_u,
                       g_o, be_o, m_o, v_o, (float*)d_out);
}

// Round 8
// 136.895 us; speedup vs baseline: 1.2029x; 1.0058x over previous
//
#include <hip/hip_runtime.h>

#define NN   16000
#define NE   64000
#define DIN  256
#define HD   64
#define DOUT 256
#define DE   128
#define KHD  32
#define BN_EPS 1e-5f

typedef __attribute__((ext_vector_type(8))) short bf16x8;
typedef __attribute__((ext_vector_type(4))) float f32x4;

__device__ __forceinline__ unsigned short f2bf(float f) {
    unsigned int u = __float_as_uint(f);
    u += 0x7fff + ((u >> 16) & 1);
    return (unsigned short)(u >> 16);
}
__device__ __forceinline__ float bf2f(unsigned short s) {
    return __uint_as_float(((unsigned int)s) << 16);
}

// ---------------- kernel P: pack all weights into bf16 MFMA layouts ----------------------
__global__ __launch_bounds__(256) void k_prep(
    const float* __restrict__ kw2, const float* __restrict__ kb2,
    const float* __restrict__ w1, const float* __restrict__ kw1, const float* __restrict__ w2,
    unsigned short* __restrict__ Wb, unsigned short* __restrict__ W0b,
    unsigned short* __restrict__ w1b, unsigned short* __restrict__ kw1b,
    unsigned short* __restrict__ w2b)
{
    int idx = blockIdx.x * 256 + threadIdx.x;
    if (idx < 33 * 4096) {
        int h = idx >> 12, r = idx & 4095;
        float v = (h < 32) ? kw2[(size_t)h * 4160 + 64 + r] : kb2[64 + r];
        Wb[idx] = f2bf(v);
        return;
    }
    idx -= 33 * 4096;
    if (idx < 2048) { int j = idx >> 5, h = idx & 31; W0b[idx] = f2bf(kw2[(size_t)h * 4160 + j]); return; }
    idx -= 2048;
    if (idx < 16384) { int j = idx >> 8, k = idx & 255; w1b[idx] = f2bf(w1[(size_t)k * 64 + j]); return; }
    idx -= 16384;
    if (idx < 4096) { int h = idx >> 7, k = idx & 127; kw1b[idx] = f2bf(kw1[(size_t)k * 32 + h]); return; }
    idx -= 4096;
    if (idx < 16384) { int c = idx >> 6, k = idx & 63; w2b[idx] = f2bf(w2[(size_t)k * 256 + c]); return; }
}

// ---------------- kernel A: msgn_b = bf16(relu(bn_msg(relu(bn_in(x)) @ w1 + b1))) --------
#define LNS 264
__global__ __launch_bounds__(256) void k_msgn(
    const float* __restrict__ x, const unsigned short* __restrict__ w1b,
    const float* __restrict__ b1,
    const float* __restrict__ g_in, const float* __restrict__ be_in,
    const float* __restrict__ m_in, const float* __restrict__ v_in,
    const float* __restrict__ g_m, const float* __restrict__ be_m,
    const float* __restrict__ m_m, const float* __restrict__ v_m,
    unsigned short* __restrict__ msgn_b)
{
    __shared__ __align__(16) unsigned short lnb[64 * LNS];
    __shared__ __align__(16) float sc_in[DIN], sh_in[DIN], sc_m[HD], shm2[HD];
    const int t = threadIdx.x;
    const int n0 = blockIdx.x * 64;
    {
        float s = g_in[t] * rsqrtf(v_in[t] + BN_EPS);
        sc_in[t] = s; sh_in[t] = be_in[t] - m_in[t] * s;
        if (t < HD) {
            float s2 = g_m[t] * rsqrtf(v_m[t] + BN_EPS);
            sc_m[t] = s2; shm2[t] = b1[t] * s2 + (be_m[t] - m_m[t] * s2);
        }
    }
    __syncthreads();
    for (int i = t; i < 64 * 64; i += 256) {
        int row = i >> 6, c4 = (i & 63) * 4;
        float4 xx = *(const float4*)(x + (size_t)(n0 + row) * DIN + c4);
        float4 sc = *(const float4*)(sc_in + c4);
        float4 sh = *(const float4*)(sh_in + c4);
        ushort4 o;
        o.x = f2bf(fmaxf(fmaf(xx.x, sc.x, sh.x), 0.f));
        o.y = f2bf(fmaxf(fmaf(xx.y, sc.y, sh.y), 0.f));
        o.z = f2bf(fmaxf(fmaf(xx.z, sc.z, sh.z), 0.f));
        o.w = f2bf(fmaxf(fmaf(xx.w, sc.w, sh.w), 0.f));
        *(ushort4*)(lnb + row * LNS + c4) = o;
    }
    __syncthreads();
    const int w = t >> 6, le = t & 15, g = (t >> 4) & 3;
    const f32x4 zz = {0.f, 0.f, 0.f, 0.f};
    f32x4 acc[4] = {zz, zz, zz, zz};
#pragma unroll
    for (int ks = 0; ks < 8; ++ks) {
        bf16x8 b = *(const bf16x8*)(lnb + (w * 16 + le) * LNS + ks * 32 + g * 8);
#pragma unroll
        for (int jt = 0; jt < 4; ++jt) {
            bf16x8 a = *(const bf16x8*)(w1b + (jt * 16 + le) * 256 + ks * 32 + g * 8);
            acc[jt] = __builtin_amdgcn_mfma_f32_16x16x32_bf16(a, b, acc[jt], 0, 0, 0);
        }
    }
    const int n = n0 + w * 16 + le;
#pragma unroll
    for (int jt = 0; jt < 4; ++jt) {
        int j = jt * 16 + g * 4;
        float4 sc = *(const float4*)(sc_m + j);
        float4 sh = *(const float4*)(shm2 + j);
        ushort4 o;
        o.x = f2bf(fmaxf(fmaf(acc[jt][0], sc.x, sh.x), 0.f));
        o.y = f2bf(fmaxf(fmaf(acc[jt][1], sc.y, sh.y), 0.f));
        o.z = f2bf(fmaxf(fmaf(acc[jt][2], sc.z, sh.z), 0.f));
        o.w = f2bf(fmaxf(fmaf(acc[jt][3], sc.w, sh.w), 0.f));
        *(ushort4*)(msgn_b + (size_t)n * HD + j) = o;
    }
}

// ---------------- kernel B: hid_b = bf16(relu(ei @ kw1 + kb1)) ---------------------------
#define EIS 136
__global__ __launch_bounds__(256) void k_hidden(
    const float* __restrict__ ei, const unsigned short* __restrict__ kw1b,
    const float* __restrict__ kb1, unsigned short* __restrict__ hid_b)
{
    __shared__ __align__(16) unsigned short eib[64 * EIS];
    __shared__ float kb1s[KHD];
    const int t = threadIdx.x;
    const int e0 = blockIdx.x * 64;
    if (t < KHD) kb1s[t] = kb1[t];
    for (int i = t; i < 64 * 32; i += 256) {
        int row = i >> 5, c4 = (i & 31) * 4;
        float4 xx = *(const float4*)(ei + (size_t)(e0 + row) * DE + c4);
        ushort4 o;
        o.x = f2bf(xx.x); o.y = f2bf(xx.y); o.z = f2bf(xx.z); o.w = f2bf(xx.w);
        *(ushort4*)(eib + row * EIS + c4) = o;
    }
    __syncthreads();
    const int w = t >> 6, le = t & 15, g = (t >> 4) & 3;
    const f32x4 zz = {0.f, 0.f, 0.f, 0.f};
    f32x4 acc[2] = {zz, zz};
#pragma unroll
    for (int ks = 0; ks < 4; ++ks) {
        bf16x8 b = *(const bf16x8*)(eib + (w * 16 + le) * EIS + ks * 32 + g * 8);
#pragma unroll
        for (int jt = 0; jt < 2; ++jt) {
            bf16x8 a = *(const bf16x8*)(kw1b + (jt * 16 + le) * 128 + ks * 32 + g * 8);
            acc[jt] = __builtin_amdgcn_mfma_f32_16x16x32_bf16(a, b, acc[jt], 0, 0, 0);
        }
    }
    const int e = e0 + w * 16 + le;
#pragma unroll
    for (int jt = 0; jt < 2; ++jt) {
        int h = jt * 16 + g * 4;
        ushort4 o;
        o.x = f2bf(fmaxf(acc[jt][0] + kb1s[h + 0], 0.f));
        o.y = f2bf(fmaxf(acc[jt][1] + kb1s[h + 1], 0.f));
        o.z = f2bf(fmaxf(acc[jt][2] + kb1s[h + 2], 0.f));
        o.w = f2bf(fmaxf(acc[jt][3] + kb1s[h + 3], 0.f));
        *(ushort4*)(hid_b + (size_t)e * KHD + h) = o;
    }
}

// ---------------- CSR build --------------------------------------------------------------
__global__ __launch_bounds__(256) void k_deg(const int* __restrict__ elist, int* __restrict__ deg) {
    int e = blockIdx.x * 256 + threadIdx.x;
    if (e < NE) atomicAdd(&deg[elist[(size_t)e * 2 + 1]], 1);
}

__global__ __launch_bounds__(1024) void k_scan(const int* __restrict__ deg,
                                               int* __restrict__ rowptr, int* __restrict__ cursor) {
    __shared__ int part[1024];
    const int t = threadIdx.x;
    const int base = t * 16;
    int loc[16]; int s = 0;
#pragma unroll
    for (int i = 0; i < 16; ++i) {
        int idx = base + i;
        int v = (idx < NN) ? deg[idx] : 0;
        loc[i] = s; s += v;
    }
    part[t] = s;
    __syncthreads();
    for (int off = 1; off < 1024; off <<= 1) {
        int v = (t >= off) ? part[t - off] : 0;
        __syncthreads();
        part[t] += v;
        __syncthreads();
    }
    int pre = (t == 0) ? 0 : part[t - 1];
#pragma unroll
    for (int i = 0; i < 16; ++i) {
        int idx = base + i;
        if (idx < NN) { rowptr[idx] = pre + loc[i]; cursor[idx] = pre + loc[i]; }
    }
    if (t == 1023) rowptr[NN] = part[1023];
}

__global__ __launch_bounds__(256) void k_place(const int* __restrict__ elist,
                                               int* __restrict__ cursor, int* __restrict__ epos) {
    int e = blockIdx.x * 256 + threadIdx.x;
    if (e < NE) {
        int n = elist[(size_t)e * 2 + 1];
        epos[e] = atomicAdd(&cursor[n], 1);
    }
}

// ---------------- kernel D: fused bilinear via MFMA (64 edges/block, 4 waves) ------------
// Round-5 proven structure + per-block ROTATED h-order (start h = blockIdx%33) to
// de-hotspot the shared Wb stream in L2 (all blocks otherwise read the same row
// at the same time in lockstep).
#define HS 36
__global__ __launch_bounds__(256) void k_edge(
    const unsigned short* __restrict__ msgn_b,   // [NN][64]
    const unsigned short* __restrict__ hid_b,    // [NE][32]
    const int* __restrict__ elist, const float* __restrict__ eweight,
    const int* __restrict__ epos,
    const unsigned short* __restrict__ Wb,       // [33][64][64]
    const unsigned short* __restrict__ W0b,      // [64][32]
    const float* __restrict__ kb2,
    unsigned short* __restrict__ msg_out)        // [NE][64] bf16, CSR-permuted, *eweight
{
    __shared__ __align__(16) float hids[64 * HS];
    const int t = threadIdx.x;
    const int w = t >> 6, le = t & 15, g = (t >> 4) & 3;
    const int e0 = blockIdx.x * 64;

    for (int q = t; q < 512; q += 256) {
        int e = q >> 3, h4 = (q & 7) * 4;
        ushort4 hh = *(const ushort4*)(hid_b + (size_t)(e0 + e) * KHD + h4);
        float4 f; f.x = bf2f(hh.x); f.y = bf2f(hh.y); f.z = bf2f(hh.z); f.w = bf2f(hh.w);
        *(float4*)(hids + e * HS + h4) = f;
    }
    if (t < 64) hids[t * HS + 32] = 1.0f;

    int eid[4], ep[4];
#pragma unroll
    for (int nt = 0; nt < 4; ++nt) {
        eid[nt] = e0 + nt * 16 + le;
        ep[nt] = epos[eid[nt]];
    }

    bf16x8 bm[4][2];
#pragma unroll
    for (int nt = 0; nt < 4; ++nt) {
        int ni = elist[(size_t)eid[nt] * 2];
#pragma unroll
        for (int ks = 0; ks < 2; ++ks)
            bm[nt][ks] = *(const bf16x8*)(msgn_b + (size_t)ni * HD + ks * 32 + g * 8);
    }

    const f32x4 zz = {0.f, 0.f, 0.f, 0.f};
    f32x4 acc[4];
    {   // r=0 block: A[j][h]=kw2[h,j], B=hid (bf16), K=32
        bf16x8 a0 = *(const bf16x8*)(W0b + (w * 16 + le) * KHD + g * 8);
#pragma unroll
        for (int nt = 0; nt < 4; ++nt) {
            bf16x8 hb = *(const bf16x8*)(hid_b + (size_t)eid[nt] * KHD + g * 8);
            acc[nt] = __builtin_amdgcn_mfma_f32_16x16x32_bf16(a0, hb, zz, 0, 0, 0);
        }
    }
    __syncthreads();

    // ---- h-loop, rotated start per block ----
    int hr = (int)(blockIdx.x % 33u);
#pragma unroll 3
    for (int it = 0; it < 33; ++it) {
        float hv[4];
#pragma unroll
        for (int nt = 0; nt < 4; ++nt) hv[nt] = hids[(nt * 16 + le) * HS + hr];
        const unsigned short* wh = Wb + (size_t)hr * 4096 + (w * 16 + le) * 64;
        bf16x8 a0 = *(const bf16x8*)(wh + g * 8);
        bf16x8 a1 = *(const bf16x8*)(wh + 32 + g * 8);
#pragma unroll
        for (int nt = 0; nt < 4; ++nt) {
            f32x4 c = __builtin_amdgcn_mfma_f32_16x16x32_bf16(a0, bm[nt][0], zz, 0, 0, 0);
            c = __builtin_amdgcn_mfma_f32_16x16x32_bf16(a1, bm[nt][1], c, 0, 0, 0);
            acc[nt] += hv[nt] * c;
        }
        hr = (hr == 32) ? 0 : hr + 1;
    }

    const int j = w * 16 + g * 4;
    float4 kbv = *(const float4*)(kb2 + j);
#pragma unroll
    for (int nt = 0; nt < 4; ++nt) {
        float ew = eweight[eid[nt]];
        ushort4 o;
        o.x = f2bf((acc[nt][0] + kbv.x) * ew);
        o.y = f2bf((acc[nt][1] + kbv.y) * ew);
        o.z = f2bf((acc[nt][2] + kbv.z) * ew);
        o.w = f2bf((acc[nt][3] + kbv.w) * ew);
        *(ushort4*)(msg_out + (size_t)ep[nt] * HD + j) = o;
    }
}

// ---------------- kernel E: streaming segment-sum + bn_upd/relu + MFMA GEMM + bn_out -----
#define UTS 72
__global__ __launch_bounds__(256) void k_out(
    const unsigned short* __restrict__ msg_out,  // CSR-ordered
    const int* __restrict__ rowptr,
    const unsigned short* __restrict__ w2b, const float* __restrict__ b2,
    const float* __restrict__ g_u, const float* __restrict__ be_u,
    const float* __restrict__ m_u, const float* __restrict__ v_u,
    const float* __restrict__ g_o, const float* __restrict__ be_o,
    const float* __restrict__ m_o, const float* __restrict__ v_o,
    float* __restrict__ out)
{
    __shared__ __align__(16) unsigned short utb[64 * UTS];
    __shared__ __align__(16) float sc_o[DOUT], sho2[DOUT], sc_u[HD], sh_u[HD];
    const int t = threadIdx.x;
    const int n0 = blockIdx.x * 64;
    {
        float s = g_o[t] * rsqrtf(v_o[t] + BN_EPS);
        sc_o[t] = s; sho2[t] = b2[t] * s + (be_o[t] - m_o[t] * s);
        if (t < HD) {
            float s2 = g_u[t] * rsqrtf(v_u[t] + BN_EPS);
            sc_u[t] = s2; sh_u[t] = be_u[t] - m_u[t] * s2;
        }
    }
    __syncthreads();
    {
        const int j = t & 63, qw = t >> 6;
        for (int r = qw; r < 64; r += 4) {
            int n = n0 + r;
            int p0 = rowptr[n], p1 = rowptr[n + 1];
            float a = 0.f;
            for (int p = p0; p < p1; ++p)
                a += bf2f(msg_out[(size_t)p * HD + j]);
            utb[r * UTS + j] = f2bf(fmaxf(fmaf(a, sc_u[j], sh_u[j]), 0.f));
        }
    }
    __syncthreads();
    const int w = t >> 6, le = t & 15, g = (t >> 4) & 3;
    const f32x4 zz = {0.f, 0.f, 0.f, 0.f};
    f32x4 acc[4][4];
#pragma unroll
    for (int jt = 0; jt < 4; ++jt)
#pragma unroll
        for (int nt = 0; nt < 4; ++nt) acc[jt][nt] = zz;
#pragma unroll
    for (int ks = 0; ks < 2; ++ks) {
        bf16x8 b[4];
#pragma unroll
        for (int nt = 0; nt < 4; ++nt)
            b[nt] = *(const bf16x8*)(utb + (nt * 16 + le) * UTS + ks * 32 + g * 8);
#pragma unroll
        for (int jt = 0; jt < 4; ++jt) {
            bf16x8 a = *(const bf16x8*)(w2b + (size_t)(w * 64 + jt * 16 + le) * HD + ks * 32 + g * 8);
#pragma unroll
            for (int nt = 0; nt < 4; ++nt)
                acc[jt][nt] = __builtin_amdgcn_mfma_f32_16x16x32_bf16(a, b[nt], acc[jt][nt], 0, 0, 0);
        }
    }
#pragma unroll
    for (int jt = 0; jt < 4; ++jt) {
        int c = w * 64 + jt * 16 + g * 4;
        float4 sc = *(const float4*)(sc_o + c);
        float4 sh = *(const float4*)(sho2 + c);
#pragma unroll
        for (int nt = 0; nt < 4; ++nt) {
            int n = n0 + nt * 16 + le;
            float4 o;
            o.x = fmaf(acc[jt][nt][0], sc.x, sh.x);
            o.y = fmaf(acc[jt][nt][1], sc.y, sh.y);
            o.z = fmaf(acc[jt][nt][2], sc.z, sh.z);
            o.w = fmaf(acc[jt][nt][3], sc.w, sh.w);
            *(float4*)(out + (size_t)n * DOUT + c) = o;
        }
    }
}

extern "C" void kernel_launch(void* const* d_in, const int* in_sizes, int n_in,
                              void* d_out, int out_size, void* d_ws, size_t ws_size,
                              hipStream_t stream)
{
    (void)in_sizes; (void)n_in; (void)out_size; (void)ws_size;
    const float* x    = (const float*)d_in[0];
    const float* ei   = (const float*)d_in[1];
    const int*   el   = (const int*)  d_in[2];
    const float* ew   = (const float*)d_in[3];
    const float* w1   = (const float*)d_in[4];
    const float* b1   = (const float*)d_in[5];
    const float* kw1  = (const float*)d_in[6];
    const float* kb1  = (const float*)d_in[7];
    const float* kw2  = (const float*)d_in[8];
    const float* kb2  = (const float*)d_in[9];
    const float* w2   = (const float*)d_in[10];
    const float* b2   = (const float*)d_in[11];
    const float* g_in = (const float*)d_in[12], *be_in = (const float*)d_in[13];
    const float* m_in = (const float*)d_in[14], *v_in  = (const float*)d_in[15];
    const float* g_m  = (const float*)d_in[16], *be_m  = (const float*)d_in[17];
    const float* m_m  = (const float*)d_in[18], *v_m   = (const float*)d_in[19];
    const float* g_u  = (const float*)d_in[20], *be_u  = (const float*)d_in[21];
    const float* m_u  = (const float*)d_in[22], *v_u   = (const float*)d_in[23];
    const float* g_o  = (const float*)d_in[24], *be_o  = (const float*)d_in[25];
    const float* m_o  = (const float*)d_in[26], *v_o   = (const float*)d_in[27];

    char* wsb = (char*)d_ws;
    size_t off = 0;
    auto alloc = [&](size_t bytes) -> void* {
        void* p = wsb + off; off += (bytes + 255) & ~(size_t)255; return p;
    };
    unsigned short* msgn_b  = (unsigned short*)alloc((size_t)NN * HD * 2);
    unsigned short* hid_b   = (unsigned short*)alloc((size_t)NE * KHD * 2);
    unsigned short* Wb      = (unsigned short*)alloc((size_t)33 * 4096 * 2);
    unsigned short* W0b     = (unsigned short*)alloc((size_t)64 * KHD * 2);
    unsigned short* w1b     = (unsigned short*)alloc((size_t)HD * DIN * 2);
    unsigned short* kw1b    = (unsigned short*)alloc((size_t)KHD * DE * 2);
    unsigned short* w2b     = (unsigned short*)alloc((size_t)DOUT * HD * 2);
    int* rowptr = (int*)alloc((size_t)(NN + 1) * 4);
    int* epos   = (int*)alloc((size_t)NE * 4);
    // union: deg+cursor live only until k_place; msg_out written after (k_edge)
    char* un = (char*)alloc((size_t)NE * HD * 2);
    unsigned short* msg_out = (unsigned short*)un;
    int* deg    = (int*)un;
    int* cursor = (int*)(un + (((size_t)NN * 4 + 255) & ~(size_t)255));

    hipMemsetAsync(deg, 0, (size_t)NN * 4, stream);
    hipLaunchKernelGGL(k_prep, dim3(680), dim3(256), 0, stream,
                       kw2, kb2, w1, kw1, w2, Wb, W0b, w1b, kw1b, w2b);
    hipLaunchKernelGGL(k_deg, dim3(NE / 256), dim3(256), 0, stream, el, deg);
    hipLaunchKernelGGL(k_scan, dim3(1), dim3(1024), 0, stream, deg, rowptr, cursor);
    hipLaunchKernelGGL(k_place, dim3(NE / 256), dim3(256), 0, stream, el, cursor, epos);
    hipLaunchKernelGGL(k_msgn, dim3(NN / 64), dim3(256), 0, stream,
                       x, w1b, b1, g_in, be_in, m_in, v_in, g_m, be_m, m_m, v_m, msgn_b);
    hipLaunchKernelGGL(k_hidden, dim3(NE / 64), dim3(256), 0, stream,
                       ei, kw1b, kb1, hid_b);
    hipLaunchKernelGGL(k_edge, dim3(NE / 64), dim3(256), 0, stream,
                       msgn_b, hid_b, el, ew, epos, Wb, W0b, kb2, msg_out);
    hipLaunchKernelGGL(k_out, dim3(NN / 64), dim3(256), 0, stream,
                       msg_out, rowptr, w2b, b2, g_u, be_u, m_u, v_u,
                       g_o, be_o, m_o, v_o, (float*)d_out);
}